// Round 9
// baseline (96.022 us; speedup 1.0000x reference)
//
#include <hip/hip_runtime.h>
#include <hip/hip_bf16.h>
#include <hip/hip_fp16.h>
#include <math.h>

#define D_MODEL 1024
#define NMOD 8
#define BATCH 8
#define NNODE 8192
#define PI_F 3.14159265358979323846f
#define MAXT 3.0f

typedef short bf16x8 __attribute__((ext_vector_type(8)));
typedef float f32x4 __attribute__((ext_vector_type(4)));

__device__ inline unsigned short f2bf(float x) {
    __hip_bfloat16 h = __float2bfloat16(x);   // RNE
    return __builtin_bit_cast(unsigned short, h);
}
__device__ inline float h2f(unsigned short u) {
    __half h = __builtin_bit_cast(__half, u);
    return __half2float(h);
}
__device__ inline unsigned short f2h(float x) {
    __half h = __float2half(x);
    return __builtin_bit_cast(unsigned short, h);
}

// ---------------- kernel 0: pack W (bf16) into MFMA B-fragment lane order
// Also zeroes the per-batch completion counters (kernel-end flush makes this
// visible to the fused kernel launched after it in-stream).
__global__ void pack_b(const float* __restrict__ W, unsigned short* __restrict__ Bpk,
                       int* __restrict__ cnt) {
    int t = blockIdx.x * 256 + threadIdx.x;   // 8192 total
    if (t < BATCH) cnt[t] = 0;
    int l  = t & 63;
    int g  = (t >> 6) & 3;
    int ks = t >> 8;
    int j  = g * 16 + (l & 15);
    int k0 = ks * 32 + ((l >> 4) * 8);
    const float* wp = &W[(size_t)j * D_MODEL + k0];
    bf16x8 pack;
    #pragma unroll
    for (int r = 0; r < 8; ++r) pack[r] = (short)f2bf(wp[r]);
    *reinterpret_cast<bf16x8*>(Bpk + (size_t)t * 8) = pack;
}

// granule = 2 ks (64 k-floats); per lane 4 float4 = 16 VGPR
__device__ __forceinline__ void loadg2(float4 (&dst)[4], const float* arow, int g) {
    #pragma unroll
    for (int i = 0; i < 2; ++i) {
        dst[2 * i]     = *reinterpret_cast<const float4*>(arow + (g * 2 + i) * 32);
        dst[2 * i + 1] = *reinterpret_cast<const float4*>(arow + (g * 2 + i) * 32 + 4);
    }
}

// ---------------- fused kernel: blocks 0..255 = gemm, 256..263 = scan
__global__ __launch_bounds__(1024) void fused(
    const float* __restrict__ feats, const unsigned short* __restrict__ Bpk,
    const float* __restrict__ bias, const float* __restrict__ coords,
    unsigned int* __restrict__ esp,        // packed {fp16 sp | fp16 ew}
    float* __restrict__ partials,          // [8][32][64]
    int* __restrict__ cnt,                 // [8]
    float* __restrict__ out)
{
    __shared__ __align__(16) unsigned char smem[131072];
    const int bid  = blockIdx.x;
    const int tid  = threadIdx.x;
    const int lane = tid & 63;
    const int wv   = tid >> 6;          // 0..15

    if (bid < 256) {
        // ================= GEMM role =================
        // stage all of packed W (128 KB) into LDS, linear layout (one-time)
        {
            const char* gsrc = (const char*)Bpk;
            #pragma unroll
            for (int r = 0; r < 8; ++r) {
                const int off = r * 16384 + wv * 1024;
                __builtin_amdgcn_global_load_lds(
                    (const __attribute__((address_space(1))) unsigned int*)(gsrc + off + lane * 16),
                    (__attribute__((address_space(3))) unsigned int*)(smem + off),
                    16, 0, 0);
            }
        }

        const int mt    = bid * 16 + wv;
        const int mbase = mt * 16;
        const float* arow = feats + (size_t)(mbase + (lane & 15)) * D_MODEL + ((lane >> 4) * 8);
        const unsigned short* Blds = (const unsigned short*)smem;

        f32x4 acc[4];
        #pragma unroll
        for (int g = 0; g < 4; ++g) acc[g] = (f32x4){0.f, 0.f, 0.f, 0.f};

        float4 Ab[4][4];                    // depth-4 rotating granule buffers
        #pragma unroll
        for (int i = 0; i < 4; ++i) loadg2(Ab[i], arow, i);

        __syncthreads();                    // B staged

        #pragma unroll
        for (int i = 0; i < 16; ++i) {      // 16 granules x 2 ks = 32 ks
            {   // consume granule i from Ab[i&3] (B via lgkmcnt queue)
                const float4 (&src)[4] = Ab[i & 3];
                #pragma unroll
                for (int ii = 0; ii < 2; ++ii) {
                    float f[8] = {src[2*ii].x, src[2*ii].y, src[2*ii].z, src[2*ii].w,
                                  src[2*ii+1].x, src[2*ii+1].y, src[2*ii+1].z, src[2*ii+1].w};
                    bf16x8 a;
                    #pragma unroll
                    for (int j = 0; j < 8; ++j) a[j] = (short)f2bf(f[j]);
                    const int ks = i * 2 + ii;
                    #pragma unroll
                    for (int gg = 0; gg < 4; ++gg) {
                        bf16x8 bh = *reinterpret_cast<const bf16x8*>(
                            Blds + ((size_t)((ks * 4 + gg) * 64 + lane)) * 8);
                        acc[gg] = __builtin_amdgcn_mfma_f32_16x16x32_bf16(a, bh, acc[gg], 0, 0, 0);
                    }
                }
            }
            if (i + 4 < 16) loadg2(Ab[i & 3], arow, i + 4);
        }

        // epilogue: alias dead B region as pbuf + sacc
        __syncthreads();
        float* pbuf = reinterpret_cast<float*>(smem) + (size_t)wv * (16 * 68);
        float* sacc = reinterpret_cast<float*>(smem + 69632);
        if (tid < 64) sacc[tid] = 0.f;

        #pragma unroll
        for (int g = 0; g < 4; ++g) {
            float bj = bias[g * 16 + (lane & 15)];
            #pragma unroll
            for (int r = 0; r < 4; ++r)
                pbuf[((lane >> 4) * 4 + r) * 68 + g * 16 + (lane & 15)] = acc[g][r] + bj;
        }
        __syncthreads();

        const int b    = mbase >> 13;
        const int nInB = mbase & 8191;

        #pragma unroll
        for (int h = 0; h < 2; ++h) {
            const int node = lane & 15;
            const int m    = (lane >> 4) + 4 * h;
            const float* pa = &pbuf[node * 68 + m * 8];
            float al = pa[0], sl = pa[1];
            float ax = pa[2], ay = pa[3], az = pa[4];
            float tx = pa[5], ty = pa[6], tz = pa[7];

            float ew = expf(al);
            float sp = 1.f / (1.f + expf(-sl));

            float n0  = sqrtf(ax * ax + ay * ay + az * az);
            float inv = 1.f / fmaxf(n0, 1e-12f);
            float ang = tanhf(n0) * PI_F;
            float hf  = 0.5f * ang;
            float shoa = (ang < 1e-6f) ? (0.5f - ang * ang * (1.f / 48.f))
                                       : (sinf(hf) / ang);
            float qw = cosf(hf);
            float fac = inv * ang * shoa;
            float qx = ax * fac, qy = ay * fac, qz = az * fac;

            float ttx = tanhf(tx) * MAXT, tty = tanhf(ty) * MAXT, ttz = tanhf(tz) * MAXT;

            size_t base = ((size_t)(b * NMOD + m)) * NNODE + nInB + node;
            esp[base] = ((unsigned)f2h(sp) << 16) | (unsigned)f2h(ew);

            float red[8];
            red[0] = sp;
            red[1] = sp * qw; red[2] = sp * qx; red[3] = sp * qy; red[4] = sp * qz;
            red[5] = sp * ttx; red[6] = sp * tty; red[7] = sp * ttz;
            #pragma unroll
            for (int v = 0; v < 8; ++v) {
                #pragma unroll
                for (int o = 1; o < 16; o <<= 1) red[v] += __shfl_xor(red[v], o);
            }
            if ((lane & 15) == 0) {
                #pragma unroll
                for (int v = 0; v < 8; ++v) atomicAdd(&sacc[m * 8 + v], red[v]);
            }
        }
        __syncthreads();   // sacc complete; also drains all waves' esp stores to L2

        if (tid < 64) {
            partials[((size_t)b * 32 + (bid & 31)) * 64 + tid] = sacc[tid];
            __threadfence();                       // writeback L2 -> device coherence point
            if (tid == 0)
                __hip_atomic_fetch_add(&cnt[b], 1, __ATOMIC_RELEASE, __HIP_MEMORY_SCOPE_AGENT);
        }
    } else {
        // ================= SCAN role (one block per batch) =================
        const int b = bid - 256;
        float* redbuf = reinterpret_cast<float*>(smem);        // 64
        float* bcast  = reinterpret_cast<float*>(smem) + 64;   // 4
        float* smod   = reinterpret_cast<float*>(smem) + 96;   // 64

        const int n0 = tid * 8;
        const int wid = wv;

        float cx[8], cy[8], cz[8];
        {
            float c[24];
            const float4* cp4 = reinterpret_cast<const float4*>(
                &coords[((size_t)b * NNODE + n0) * 3]);
            #pragma unroll
            for (int q = 0; q < 6; ++q) {
                float4 v = cp4[q];
                c[q * 4 + 0] = v.x; c[q * 4 + 1] = v.y;
                c[q * 4 + 2] = v.z; c[q * 4 + 3] = v.w;
            }
            #pragma unroll
            for (int i = 0; i < 8; ++i) { cx[i] = c[3*i]; cy[i] = c[3*i+1]; cz[i] = c[3*i+2]; }
        }

        // wait for this batch's 32 gemm blocks (device-scope acquire)
        if (tid == 0) {
            while (__hip_atomic_load(&cnt[b], __ATOMIC_ACQUIRE, __HIP_MEMORY_SCOPE_AGENT) < 32)
                __builtin_amdgcn_s_sleep(8);
        }
        __syncthreads();

        // reduce the 32 per-block partials -> smod[64] (deterministic order)
        if (tid < 64) {
            float s = 0.f;
            #pragma unroll 4
            for (int blk = 0; blk < 32; ++blk)
                s += partials[((size_t)b * 32 + blk) * 64 + tid];
            smod[tid] = s;
        }
        __syncthreads();

        const uint4* esp4 = reinterpret_cast<const uint4*>(&esp[(size_t)b * NMOD * NNODE]);
        uint4 cur0 = esp4[(0 * NNODE + n0) >> 2];
        uint4 cur1 = esp4[((0 * NNODE + n0) >> 2) + 1];

        for (int m = 0; m < NMOD; ++m) {
            const int mn = (m + 1 < NMOD) ? m + 1 : m;
            uint4 nxt0 = esp4[(mn * NNODE + n0) >> 2];
            uint4 nxt1 = esp4[((mn * NNODE + n0) >> 2) + 1];

            unsigned pk[8] = {cur0.x, cur0.y, cur0.z, cur0.w, cur1.x, cur1.y, cur1.z, cur1.w};
            float ev[8], spl[8];
            #pragma unroll
            for (int i = 0; i < 8; ++i) {
                ev[i]  = h2f((unsigned short)(pk[i] & 0xFFFFu));
                spl[i] = h2f((unsigned short)(pk[i] >> 16));
            }

            float se = 0.f, sx = 0.f, sy = 0.f, sz = 0.f;
            #pragma unroll
            for (int i = 0; i < 8; ++i) {
                se += ev[i]; sx += ev[i] * cx[i]; sy += ev[i] * cy[i]; sz += ev[i] * cz[i];
            }
            float vals[4] = {se, sx, sy, sz};
            #pragma unroll
            for (int v = 0; v < 4; ++v) {
                float x = vals[v];
                #pragma unroll
                for (int o = 32; o > 0; o >>= 1) x += __shfl_down(x, o);
                if (lane == 0) redbuf[wid * 4 + v] = x;
            }
            __syncthreads();
            if (wid == 0) {
                float x = redbuf[lane];
                x += __shfl_down(x, 32);
                x += __shfl_down(x, 16);
                x += __shfl_down(x, 8);
                x += __shfl_down(x, 4);
                if (lane < 4) bcast[lane] = x;
            }
            __syncthreads();
            const float SE = bcast[0];
            const float AXc = bcast[1] / SE, AYc = bcast[2] / SE, AZc = bcast[3] / SE;

            const float* sm = &smod[m * 8];
            float s  = fmaxf(sm[0], 1e-8f);
            float qw = sm[1] / s, qx = sm[2] / s, qy = sm[3] / s, qz = sm[4] / s;
            float qn = sqrtf(qw * qw + qx * qx + qy * qy + qz * qz);
            float qi = 1.f / fmaxf(qn, 1e-12f);
            qw *= qi; qx *= qi; qy *= qi; qz *= qi;

            float xx = qx*qx, yy = qy*qy, zz = qz*qz;
            float xy = qx*qy, xz = qx*qz, yz = qy*qz;
            float wx = qw*qx, wy = qw*qy, wz = qw*qz;
            float r00 = 1.f - 2.f*(yy+zz), r01 = 2.f*(xy-wz),       r02 = 2.f*(xz+wy);
            float r10 = 2.f*(xy+wz),       r11 = 1.f - 2.f*(xx+zz), r12 = 2.f*(yz-wx);
            float r20 = 2.f*(xz-wy),       r21 = 2.f*(yz+wx),       r22 = 1.f - 2.f*(xx+yy);
            float dx = AXc + sm[5] / s, dy = AYc + sm[6] / s, dz = AZc + sm[7] / s;

            #pragma unroll
            for (int i = 0; i < 8; ++i) {
                float px = cx[i] - AXc, py = cy[i] - AYc, pz = cz[i] - AZc;
                float mx = fmaf(r00, px, fmaf(r01, py, fmaf(r02, pz, dx)));
                float my = fmaf(r10, px, fmaf(r11, py, fmaf(r12, pz, dy)));
                float mz = fmaf(r20, px, fmaf(r21, py, fmaf(r22, pz, dz)));
                float sp = spl[i];
                cx[i] = fmaf(sp, mx - cx[i], cx[i]);
                cy[i] = fmaf(sp, my - cy[i], cy[i]);
                cz[i] = fmaf(sp, mz - cz[i], cz[i]);
            }
            cur0 = nxt0; cur1 = nxt1;
            __syncthreads();
        }

        {
            float c[24];
            #pragma unroll
            for (int i = 0; i < 8; ++i) { c[3*i] = cx[i]; c[3*i+1] = cy[i]; c[3*i+2] = cz[i]; }
            float4* op4 = reinterpret_cast<float4*>(&out[((size_t)b * NNODE + n0) * 3]);
            #pragma unroll
            for (int q = 0; q < 6; ++q)
                op4[q] = make_float4(c[q*4+0], c[q*4+1], c[q*4+2], c[q*4+3]);
        }
    }
}

extern "C" void kernel_launch(void* const* d_in, const int* in_sizes, int n_in,
                              void* d_out, int out_size, void* d_ws, size_t ws_size,
                              hipStream_t stream) {
    const float* feats  = (const float*)d_in[0];
    const float* coords = (const float*)d_in[1];
    const float* W      = (const float*)d_in[2];
    const float* bias   = (const float*)d_in[3];
    float* out = (float*)d_out;

    char* ws = (char*)d_ws;
    unsigned short* Bpk = (unsigned short*)(ws);                       // 128 KB (256 KB reserved)
    unsigned int* esp   = (unsigned int*)(ws + 262144);                // 2 MB packed {sp|ew}
    float* partials     = (float*)(ws + 262144 + 2097152);             // 64 KB [8][32][64]
    int* cnt            = (int*)(ws + 262144 + 2097152 + 65536);       // 8 ints

    pack_b<<<32, 256, 0, stream>>>(W, Bpk, cnt);
    fused<<<264, 1024, 0, stream>>>(feats, Bpk, bias, coords, esp, partials, cnt, out);
}

// Round 10
// 91.005 us; speedup vs baseline: 1.0551x; 1.0551x over previous
//
#include <hip/hip_runtime.h>
#include <hip/hip_bf16.h>
#include <hip/hip_fp16.h>
#include <math.h>

#define D_MODEL 1024
#define NMOD 8
#define BATCH 8
#define NNODE 8192
#define PI_F 3.14159265358979323846f
#define MAXT 3.0f

typedef short bf16x8 __attribute__((ext_vector_type(8)));
typedef float f32x4 __attribute__((ext_vector_type(4)));

__device__ inline unsigned short f2bf(float x) {
    __hip_bfloat16 h = __float2bfloat16(x);   // RNE
    return __builtin_bit_cast(unsigned short, h);
}
__device__ inline float h2f(unsigned short u) {
    __half h = __builtin_bit_cast(__half, u);
    return __half2float(h);
}
__device__ inline unsigned short f2h(float x) {
    __half h = __float2half(x);
    return __builtin_bit_cast(unsigned short, h);
}

// ---------------- kernel 0: pack W (bf16) into MFMA B-fragment lane order
// Also zeroes the sums buffer. Entry e = (ks*4 + g)*64 + lane, 8 ushorts each.
// Lane l, reg r holds B[k = ks*32 + (l>>4)*8 + r][col j = g*16 + (l&15)] = W[j][k]
__global__ void pack_b(const float* __restrict__ W, unsigned short* __restrict__ Bpk,
                       float* __restrict__ sums) {
    int t = blockIdx.x * 256 + threadIdx.x;   // 8192 total
    if (t < BATCH * NMOD * 8) sums[t] = 0.f;  // 512 floats
    int l  = t & 63;
    int g  = (t >> 6) & 3;
    int ks = t >> 8;
    int j  = g * 16 + (l & 15);
    int k0 = ks * 32 + ((l >> 4) * 8);
    const float* wp = &W[(size_t)j * D_MODEL + k0];
    bf16x8 pack;
    #pragma unroll
    for (int r = 0; r < 8; ++r) pack[r] = (short)f2bf(wp[r]);
    *reinterpret_cast<bf16x8*>(Bpk + (size_t)t * 8) = pack;
}

// granule = 2 ks (64 k-floats); per lane 4 float4 = 16 VGPR
__device__ __forceinline__ void loadg2(float4 (&dst)[4], const float* arow, int g) {
    #pragma unroll
    for (int i = 0; i < 2; ++i) {
        dst[2 * i]     = *reinterpret_cast<const float4*>(arow + (g * 2 + i) * 32);
        dst[2 * i + 1] = *reinterpret_cast<const float4*>(arow + (g * 2 + i) * 32 + 4);
    }
}

// B from LDS (lgkmcnt queue) -> consuming B never drains the A vmcnt queue
__device__ __forceinline__ void compg2(const float4 (&src)[4], int g,
                                       const unsigned short* __restrict__ Blds, int lane,
                                       f32x4 (&acc)[4]) {
    #pragma unroll
    for (int i = 0; i < 2; ++i) {
        float f[8] = {src[2*i].x, src[2*i].y, src[2*i].z, src[2*i].w,
                      src[2*i+1].x, src[2*i+1].y, src[2*i+1].z, src[2*i+1].w};
        bf16x8 a;
        #pragma unroll
        for (int j = 0; j < 8; ++j) a[j] = (short)f2bf(f[j]);
        const int ks = g * 2 + i;
        #pragma unroll
        for (int gg = 0; gg < 4; ++gg) {
            bf16x8 bh = *reinterpret_cast<const bf16x8*>(
                Blds + ((size_t)((ks * 4 + gg) * 64 + lane)) * 8);
            acc[gg] = __builtin_amdgcn_mfma_f32_16x16x32_bf16(a, bh, acc[gg], 0, 0, 0);
        }
    }
}

// ---------------- kernel A: bf16 MFMA GEMM, whole W in LDS, depth-4 A prefetch
// __launch_bounds__(1024, 4): 4 waves/EU = 16 waves/CU = exactly our 1-block/CU
// occupancy (LDS-forced anyway) -> VGPR cap 128, the depth-4 pipeline fits in
// registers. Without the 2nd arg the compiler capped at ~52 VGPR (R9 counters)
// and silently collapsed the prefetch pipeline.
__global__ __launch_bounds__(1024, 4) void gemm_mfma(
    const float* __restrict__ feats, const unsigned short* __restrict__ Bpk,
    const float* __restrict__ bias,
    unsigned int* __restrict__ esp_out,    // packed {fp16 sp | fp16 ew}
    float* __restrict__ sums)
{
    __shared__ __align__(16) unsigned char smem[131072];   // B (main) / pbuf+sacc (epilogue)

    const int tid  = threadIdx.x;
    const int lane = tid & 63;
    const int wv   = tid >> 6;          // 0..15

    // ---- stage all of packed W (128 KB) into LDS, linear layout (one-time)
    {
        const char* gsrc = (const char*)Bpk;
        #pragma unroll
        for (int r = 0; r < 8; ++r) {
            const int off = r * 16384 + wv * 1024;
            __builtin_amdgcn_global_load_lds(
                (const __attribute__((address_space(1))) unsigned int*)(gsrc + off + lane * 16),
                (__attribute__((address_space(3))) unsigned int*)(smem + off),
                16, 0, 0);
        }
    }

    const int mt    = blockIdx.x * 16 + wv;   // m-tile (16 nodes); 4096 tiles total
    const int mbase = mt * 16;
    const float* arow = feats + (size_t)(mbase + (lane & 15)) * D_MODEL + ((lane >> 4) * 8);
    const unsigned short* Blds = (const unsigned short*)smem;

    f32x4 acc[4];
    #pragma unroll
    for (int g = 0; g < 4; ++g) acc[g] = (f32x4){0.f, 0.f, 0.f, 0.f};

    float4 Ab[4][4];                    // 4 rotating granule buffers (64 VGPR)
    #pragma unroll
    for (int i = 0; i < 4; ++i) loadg2(Ab[i], arow, i);

    __syncthreads();                    // B staged (drains vmcnt once)

    #pragma unroll
    for (int i = 0; i < 16; ++i) {      // 16 granules x 2 ks = 32 ks
        compg2(Ab[i & 3], i, Blds, lane, acc);
        if (i + 4 < 16) loadg2(Ab[i & 3], arow, i + 4);
    }

    // ---- epilogue: alias dead B region as pbuf (16 waves x 16 x 68 f32) + sacc
    __syncthreads();                                   // all waves done reading B
    float* pbuf = reinterpret_cast<float*>(smem) + (size_t)wv * (16 * 68);
    float* sacc = reinterpret_cast<float*>(smem + 69632);
    if (tid < 64) sacc[tid] = 0.f;

    // params -> per-wave LDS (add bias). D: row=(lane>>4)*4+reg, col=g*16+(lane&15)
    #pragma unroll
    for (int g = 0; g < 4; ++g) {
        float bj = bias[g * 16 + (lane & 15)];
        #pragma unroll
        for (int r = 0; r < 4; ++r)
            pbuf[((lane >> 4) * 4 + r) * 68 + g * 16 + (lane & 15)] = acc[g][r] + bj;
    }
    __syncthreads();                                   // sacc zero + pbuf visible

    const int b    = mbase >> 13;     // / 8192 (uniform per block; 32 blocks/batch)
    const int nInB = mbase & 8191;

    #pragma unroll
    for (int h = 0; h < 2; ++h) {
        const int node = lane & 15;
        const int m    = (lane >> 4) + 4 * h;
        const float* pa = &pbuf[node * 68 + m * 8];
        float al = pa[0], sl = pa[1];
        float ax = pa[2], ay = pa[3], az = pa[4];
        float tx = pa[5], ty = pa[6], tz = pa[7];

        float ew = expf(al);
        float sp = 1.f / (1.f + expf(-sl));

        float n0  = sqrtf(ax * ax + ay * ay + az * az);
        float inv = 1.f / fmaxf(n0, 1e-12f);
        float ang = tanhf(n0) * PI_F;
        float hf  = 0.5f * ang;
        float shoa = (ang < 1e-6f) ? (0.5f - ang * ang * (1.f / 48.f))
                                   : (sinf(hf) / ang);
        float qw = cosf(hf);
        float fac = inv * ang * shoa;
        float qx = ax * fac, qy = ay * fac, qz = az * fac;

        float ttx = tanhf(tx) * MAXT, tty = tanhf(ty) * MAXT, ttz = tanhf(tz) * MAXT;

        size_t base = ((size_t)(b * NMOD + m)) * NNODE + nInB + node;
        esp_out[base] = ((unsigned)f2h(sp) << 16) | (unsigned)f2h(ew);

        float red[8];
        red[0] = sp;
        red[1] = sp * qw; red[2] = sp * qx; red[3] = sp * qy; red[4] = sp * qz;
        red[5] = sp * ttx; red[6] = sp * tty; red[7] = sp * ttz;
        #pragma unroll
        for (int v = 0; v < 8; ++v) {
            #pragma unroll
            for (int o = 1; o < 16; o <<= 1) red[v] += __shfl_xor(red[v], o);
        }
        if ((lane & 15) == 0) {
            #pragma unroll
            for (int v = 0; v < 8; ++v) atomicAdd(&sacc[m * 8 + v], red[v]);
        }
    }
    __syncthreads();
    if (tid < 64) atomicAdd(&sums[b * 64 + tid], sacc[tid]);
}

// ---------------- kernel B: sequential 8-module scan, one block per batch
__global__ __launch_bounds__(1024, 4) void scan_coords(
    const float* __restrict__ coords,
    const unsigned int* __restrict__ esp_in,
    const float* __restrict__ sums, float* __restrict__ out)
{
    const int b   = blockIdx.x;
    const int tid = threadIdx.x;
    const int lane = tid & 63, wid = tid >> 6;
    __shared__ float redbuf[64];    // 16 waves x 4 vals
    __shared__ float bcast[4];

    const int n0 = tid * 8;         // 8 contiguous nodes per thread

    float cx[8], cy[8], cz[8];
    {
        float c[24];
        const float4* cp4 = reinterpret_cast<const float4*>(
            &coords[((size_t)b * NNODE + n0) * 3]);
        #pragma unroll
        for (int q = 0; q < 6; ++q) {
            float4 v = cp4[q];
            c[q * 4 + 0] = v.x; c[q * 4 + 1] = v.y;
            c[q * 4 + 2] = v.z; c[q * 4 + 3] = v.w;
        }
        #pragma unroll
        for (int i = 0; i < 8; ++i) { cx[i] = c[3*i]; cy[i] = c[3*i+1]; cz[i] = c[3*i+2]; }
    }

    const uint4* esp4 = reinterpret_cast<const uint4*>(
        &esp_in[(size_t)b * NMOD * NNODE]);
    uint4 cur0 = esp4[(0 * NNODE + n0) >> 2];
    uint4 cur1 = esp4[((0 * NNODE + n0) >> 2) + 1];

    for (int m = 0; m < NMOD; ++m) {
        const int mn = (m + 1 < NMOD) ? m + 1 : m;
        uint4 nxt0 = esp4[(mn * NNODE + n0) >> 2];
        uint4 nxt1 = esp4[((mn * NNODE + n0) >> 2) + 1];

        unsigned pk[8] = {cur0.x, cur0.y, cur0.z, cur0.w, cur1.x, cur1.y, cur1.z, cur1.w};
        float ev[8], spl[8];
        #pragma unroll
        for (int i = 0; i < 8; ++i) {
            ev[i]  = h2f((unsigned short)(pk[i] & 0xFFFFu));
            spl[i] = h2f((unsigned short)(pk[i] >> 16));
        }

        float se = 0.f, sx = 0.f, sy = 0.f, sz = 0.f;
        #pragma unroll
        for (int i = 0; i < 8; ++i) {
            se += ev[i]; sx += ev[i] * cx[i]; sy += ev[i] * cy[i]; sz += ev[i] * cz[i];
        }
        float vals[4] = {se, sx, sy, sz};
        #pragma unroll
        for (int v = 0; v < 4; ++v) {
            float x = vals[v];
            #pragma unroll
            for (int o = 32; o > 0; o >>= 1) x += __shfl_down(x, o);
            if (lane == 0) redbuf[wid * 4 + v] = x;
        }
        __syncthreads();
        if (wid == 0) {
            float x = redbuf[lane];              // lane = w*4+v
            x += __shfl_down(x, 32);
            x += __shfl_down(x, 16);
            x += __shfl_down(x, 8);
            x += __shfl_down(x, 4);
            if (lane < 4) bcast[lane] = x;
        }
        __syncthreads();
        const float SE = bcast[0];
        const float AXc = bcast[1] / SE, AYc = bcast[2] / SE, AZc = bcast[3] / SE;

        const float* sm = &sums[((size_t)b * NMOD + m) * 8];
        float s  = fmaxf(sm[0], 1e-8f);
        float qw = sm[1] / s, qx = sm[2] / s, qy = sm[3] / s, qz = sm[4] / s;
        float qn = sqrtf(qw * qw + qx * qx + qy * qy + qz * qz);
        float qi = 1.f / fmaxf(qn, 1e-12f);
        qw *= qi; qx *= qi; qy *= qi; qz *= qi;

        // rotation matrix from unit quaternion (uniform across threads)
        float xx = qx*qx, yy = qy*qy, zz = qz*qz;
        float xy = qx*qy, xz = qx*qz, yz = qy*qz;
        float wx = qw*qx, wy = qw*qy, wz = qw*qz;
        float r00 = 1.f - 2.f*(yy+zz), r01 = 2.f*(xy-wz),       r02 = 2.f*(xz+wy);
        float r10 = 2.f*(xy+wz),       r11 = 1.f - 2.f*(xx+zz), r12 = 2.f*(yz-wx);
        float r20 = 2.f*(xz-wy),       r21 = 2.f*(yz+wx),       r22 = 1.f - 2.f*(xx+yy);
        float dx = AXc + sm[5] / s, dy = AYc + sm[6] / s, dz = AZc + sm[7] / s;

        #pragma unroll
        for (int i = 0; i < 8; ++i) {
            float px = cx[i] - AXc, py = cy[i] - AYc, pz = cz[i] - AZc;
            float mx = fmaf(r00, px, fmaf(r01, py, fmaf(r02, pz, dx)));
            float my = fmaf(r10, px, fmaf(r11, py, fmaf(r12, pz, dy)));
            float mz = fmaf(r20, px, fmaf(r21, py, fmaf(r22, pz, dz)));
            float sp = spl[i];
            cx[i] = fmaf(sp, mx - cx[i], cx[i]);
            cy[i] = fmaf(sp, my - cy[i], cy[i]);
            cz[i] = fmaf(sp, mz - cz[i], cz[i]);
        }
        cur0 = nxt0; cur1 = nxt1;
        __syncthreads();
    }

    {
        float c[24];
        #pragma unroll
        for (int i = 0; i < 8; ++i) { c[3*i] = cx[i]; c[3*i+1] = cy[i]; c[3*i+2] = cz[i]; }
        float4* op4 = reinterpret_cast<float4*>(&out[((size_t)b * NNODE + n0) * 3]);
        #pragma unroll
        for (int q = 0; q < 6; ++q)
            op4[q] = make_float4(c[q*4+0], c[q*4+1], c[q*4+2], c[q*4+3]);
    }
}

extern "C" void kernel_launch(void* const* d_in, const int* in_sizes, int n_in,
                              void* d_out, int out_size, void* d_ws, size_t ws_size,
                              hipStream_t stream) {
    const float* feats  = (const float*)d_in[0];
    const float* coords = (const float*)d_in[1];
    const float* W      = (const float*)d_in[2];
    const float* bias   = (const float*)d_in[3];
    float* out = (float*)d_out;

    char* ws = (char*)d_ws;
    unsigned short* Bpk = (unsigned short*)(ws);                  // 128 KB (256 KB reserved)
    unsigned int* esp   = (unsigned int*)(ws + 262144);           // 2 MB packed {sp|ew}
    float* sums         = (float*)(ws + 262144 + 2097152);        // 2 KB

    pack_b<<<32, 256, 0, stream>>>(W, Bpk, sums);
    gemm_mfma<<<256, 1024, 0, stream>>>(feats, Bpk, bias, esp, sums);
    scan_coords<<<BATCH, 1024, 0, stream>>>(coords, esp, sums, out);
}